// Round 10
// baseline (233.395 us; speedup 1.0000x reference)
//
#include <hip/hip_runtime.h>
#include <cstdint>
#include <cstddef>

#define D 256
#define HEADS 8
#define HD 32
#define NB 2
#define LQ 12240
#define NQ (NB * LQ)        // 24480
#define PLANE (LQ * HD)     // 391680 elements per (n,h) plane

typedef __attribute__((ext_vector_type(8))) short bf16x8;
typedef __attribute__((ext_vector_type(4))) float f32x4;

__device__ __forceinline__ ushort f2bf(float f) {
    union { float f; uint32_t u; } c; c.f = f;
    uint32_t u = c.u;
    uint32_t r = (u + 0x7fffu + ((u >> 16) & 1u)) >> 16;   // RNE, finite inputs
    return (ushort)r;
}
__device__ __forceinline__ float bflo(uint32_t u) { return __uint_as_float(u << 16); }
__device__ __forceinline__ float bfhi(uint32_t u) { return __uint_as_float(u & 0xffff0000u); }

// ---------------------------------------------------------------------------
// K0: weight/bias conversion + src fp32->bf16 (merged; branches block-uniform).
// ---------------------------------------------------------------------------
__global__ __launch_bounds__(256) void conv_kernel(
    const float* __restrict__ w_value, const float* __restrict__ w_off,
    const float* __restrict__ w_attn,  const float* __restrict__ b_value,
    const float* __restrict__ b_off,   const float* __restrict__ b_attn,
    const float* __restrict__ w_out,   const float* __restrict__ src,
    ushort* __restrict__ B_pack, ushort* __restrict__ w_out_t,
    float* __restrict__ b_pack, ushort* __restrict__ src_bf)
{
    const int b = blockIdx.x, k = threadIdx.x;
    if (b >= 899) {
        const size_t i = ((size_t)(b - 899) * 256 + k) * 4;
        float4 v = *(const float4*)(src + i);
        ushort4 o;
        o.x = f2bf(v.x); o.y = f2bf(v.y); o.z = f2bf(v.z); o.w = f2bf(v.w);
        *(ushort4*)(src_bf + i) = o;
        return;
    }
    if (b < 640) {
        float v;
        if (b < 256)      v = w_value[(size_t)k * 256 + b];
        else if (b < 512) v = w_off[(size_t)k * 256 + (b - 256)];
        else              v = w_attn[(size_t)k * 128 + (b - 512)];
        B_pack[(size_t)b * 256 + k] = f2bf(v);
    } else if (b < 896) {
        int n = b - 640;
        w_out_t[(size_t)n * 256 + k] = f2bf(w_out[(size_t)k * 256 + n]);
    } else if (b == 896) {
        b_pack[k] = b_value[k];
    } else if (b == 897) {
        b_pack[256 + k] = b_off[k];
    } else {
        if (k < 128) b_pack[512 + k] = b_attn[k];
    }
}

// ---------------------------------------------------------------------------
// K1: fused projections via MFMA -- B-stationary in registers (unchanged,
// known good).
// ---------------------------------------------------------------------------
__global__ __launch_bounds__(256, 2) void proj_gemm(
    const ushort* __restrict__ src_bf, const ushort* __restrict__ B_pack,
    const float* __restrict__ b_pack,
    ushort* __restrict__ val_t, float* __restrict__ off_raw,
    float* __restrict__ attn_raw)
{
    const int tid = threadIdx.x;
    const int wv = tid >> 6, lane = tid & 63;
    const int quad = lane >> 4, ln = lane & 15;
    const int mc = blockIdx.x;          // 0..63
    const int by = blockIdx.y;          // 0..9

    const ushort* bp = B_pack + (size_t)(by * 64 + ln) * 256 + quad * 8;
    bf16x8 bfr[4][8];
#pragma unroll
    for (int t = 0; t < 4; ++t)
#pragma unroll
        for (int s = 0; s < 8; ++s)
            bfr[t][s] = *(const bf16x8*)(bp + (size_t)t * (16 * 256) + s * 32);

    float bias[4];
#pragma unroll
    for (int t = 0; t < 4; ++t) bias[t] = b_pack[by * 64 + t * 16 + ln];

    for (int i = 0; i < 6; ++i) {
        const int base = (mc * 6 + i) * 64;
        if (base >= NQ) break;
        const int row_a = base + wv * 16 + ln;
        const bool va = row_a < NQ;
        const ushort* ap = src_bf + (size_t)row_a * 256 + quad * 8;

        bf16x8 af[8];
#pragma unroll
        for (int s = 0; s < 8; ++s) {
            bf16x8 v = {0, 0, 0, 0, 0, 0, 0, 0};
            if (va) v = *(const bf16x8*)(ap + s * 32);
            af[s] = v;
        }

        f32x4 acc[4] = {{0,0,0,0},{0,0,0,0},{0,0,0,0},{0,0,0,0}};
#pragma unroll
        for (int s = 0; s < 8; ++s)
#pragma unroll
            for (int t = 0; t < 4; ++t)
                acc[t] = __builtin_amdgcn_mfma_f32_16x16x32_bf16(af[s], bfr[t][s], acc[t], 0, 0, 0);

        if (by < 4) {
#pragma unroll
            for (int t = 0; t < 4; ++t) {
                const int n_g = by * 64 + t * 16 + ln;
                const int h = n_g >> 5, hd = n_g & 31;
#pragma unroll
                for (int reg = 0; reg < 4; ++reg) {
                    int row = base + wv * 16 + quad * 4 + reg;
                    if (row < NQ) {
                        int nb = row >= LQ; int ql = row - nb * LQ;
                        val_t[(((size_t)(nb * 8 + h)) * LQ + ql) * 32 + hd] =
                            f2bf(acc[t][reg] + bias[t]);
                    }
                }
            }
        } else if (by < 8) {
#pragma unroll
            for (int t = 0; t < 4; ++t) {
                const int col = (by - 4) * 64 + t * 16 + ln;
#pragma unroll
                for (int reg = 0; reg < 4; ++reg) {
                    int row = base + wv * 16 + quad * 4 + reg;
                    if (row < NQ)
                        off_raw[(size_t)row * 256 + col] = acc[t][reg] + bias[t];
                }
            }
        } else {
#pragma unroll
            for (int t = 0; t < 4; ++t) {
                const int col = (by - 8) * 64 + t * 16 + ln;
#pragma unroll
                for (int reg = 0; reg < 4; ++reg) {
                    int row = base + wv * 16 + quad * 4 + reg;
                    if (row < NQ)
                        attn_raw[(size_t)row * 128 + col] = acc[t][reg] + bias[t];
                }
            }
        }
    }
}

// ---------------------------------------------------------------------------
// K1b: build x-pair table (unchanged).
// ---------------------------------------------------------------------------
__global__ __launch_bounds__(256) void pair_kernel(
    const ushort* __restrict__ val_t, uint32_t* __restrict__ val_pair)
{
    const uint32_t i = blockIdx.x * 256 + threadIdx.x;   // < 6,266,880
    const uint32_t c = i & 31;
    const uint32_t rest = i >> 5;                        // plane*12240 + pos
    const uint32_t plane = rest / LQ;
    const uint32_t pos = rest - plane * LQ;
    int l = (pos >= 9216) + (pos >= 11520) + (pos >= 12096);
    uint32_t s0 = (l > 0 ? 9216u : 0u) + (l > 1 ? 2304u : 0u) + (l > 2 ? 576u : 0u);
    uint32_t Wi = 96u >> l;
    uint32_t p = pos - s0;
    uint32_t q = (p / 3u) >> (5 - l);          // p / Wi  (Wi = 3<<(5-l))
    uint32_t xr = p - q * Wi;                  // p % Wi
    uint32_t nxt = (xr == Wi - 1u) ? pos : pos + 1u;
    uint32_t lo = val_t[(size_t)plane * PLANE + pos * 32 + c];
    uint32_t hi = val_t[(size_t)plane * PLANE + nxt * 32 + c];
    val_pair[i] = lo | (hi << 16);
}

// ---------------------------------------------------------------------------
// K2: softmax + sampling + bilinear gather.
// __launch_bounds__(256, 4) -> 128-VGPR budget: the 8-point gather batches
// (r0v/r1v = 32 VGPRs + weights 32) are genuinely register-allocated ->
// 16 loads in flight, ~2 latency round-trips per group instead of ~32
// (R9's VGPR=32 serialization).  Weights stored f32 in LDS (no bf16 weight
// unpack in hot loop).  h = blockIdx%8 XCD partition kept (R9: 3x traffic cut).
// `sampled` aliases `attn_raw` word-exactly per lane -> safe.
// ---------------------------------------------------------------------------
__global__ __launch_bounds__(256, 4) void sample_kernel(
    const float* __restrict__ ref_pts,
    const uint32_t* __restrict__ val_pair,
    const float* __restrict__ off_raw,
    const float* attn_raw,
    uint32_t* sampled)
{
    __shared__ uint2  sm_i[16][16];
    __shared__ float4 sm_w[16][16];
    const int gl = threadIdx.x >> 4;
    const int ln = threadIdx.x & 15;
    const int h     = blockIdx.x & 7;        // -> XCD id (heuristic)
    const int chunk = blockIdx.x >> 3;       // 0..1529
    const int qg = chunk * 16 + gl;
    const int n  = (qg >= LQ) ? 1 : 0;
    const int l  = ln >> 2;

    // softmax over 16 (level,point) logits of this head
    float a = attn_raw[(size_t)qg * 128 + h * 16 + ln];
    float m = a;
#pragma unroll
    for (int s = 8; s; s >>= 1) m = fmaxf(m, __shfl_xor(m, s, 16));
    float e = __expf(a - m);
    float ssum = e;
#pragma unroll
    for (int s = 8; s; s >>= 1) ssum += __shfl_xor(ssum, s, 16);
    float aw = e / ssum;

    float ox = off_raw[(size_t)qg * 256 + h * 32 + ln * 2 + 0];
    float oy = off_raw[(size_t)qg * 256 + h * 32 + ln * 2 + 1];
    float rx = ref_pts[(qg * 4 + l) * 2 + 0];
    float ry = ref_pts[(qg * 4 + l) * 2 + 1];

    const int Wi = 96 >> l;
    const int Hi = Wi;
    const int s0 = (l > 0 ? 9216 : 0) + (l > 1 ? 2304 : 0) + (l > 2 ? 576 : 0);
    const float Wf = (float)Wi, Hf = (float)Hi;

    float x = (rx + ox / Wf) * Wf - 0.5f;
    float y = (ry + oy / Hf) * Hf - 0.5f;
    float x0f = floorf(x), y0f = floorf(y);
    float lx = x - x0f, ly = y - y0f;
    int x0 = (int)x0f, y0 = (int)y0f;

    float wy0 = (y0 >= 0 && y0 < Hi) ? (1.f - ly) : 0.f;
    float wy1 = (y0 + 1 >= 0 && y0 + 1 < Hi) ? ly : 0.f;
    int yc0 = min(max(y0, 0), Hi - 1);
    int yc1 = min(max(y0 + 1, 0), Hi - 1);
    float wl = (x0 >= 0 && x0 < Wi) ? (1.f - lx) : 0.f;
    float wh = (x0 + 1 >= 0 && x0 + 1 < Wi) ? lx : 0.f;
    float pl, ph;
    int xe;
    if (x0 < 0) { pl = wh; ph = 0.f; xe = x0 + 1; }
    else        { pl = wl; ph = wh;  xe = x0; }
    int xc = min(max(xe, 0), Wi - 1);
    pl *= aw; ph *= aw;

    sm_i[gl][ln] = make_uint2((uint32_t)(s0 + yc0 * Wi + xc) * 32u,
                              (uint32_t)(s0 + yc1 * Wi + xc) * 32u);
    sm_w[gl][ln] = make_float4(pl * wy0, ph * wy0, pl * wy1, ph * wy1);
    // intra-wave LDS write->read: same-wave DS ops execute in order

    const uint32_t* plane =
        val_pair + (size_t)(n * HEADS + h) * PLANE + 2 * ln;
    float a0 = 0.f, a1 = 0.f;
#pragma unroll
    for (int c = 0; c < 2; ++c) {
        uint2  r0v[8], r1v[8];
        float4 wv[8];
#pragma unroll
        for (int p = 0; p < 8; ++p) {
            uint2 ent = sm_i[gl][c * 8 + p];
            r0v[p] = *(const uint2*)(plane + ent.x);
            r1v[p] = *(const uint2*)(plane + ent.y);
            wv[p]  = sm_w[gl][c * 8 + p];
        }
#pragma unroll
        for (int p = 0; p < 8; ++p) {
            float4 w = wv[p];
            a0 += w.x * bflo(r0v[p].x) + w.y * bfhi(r0v[p].x)
                + w.z * bflo(r1v[p].x) + w.w * bfhi(r1v[p].x);
            a1 += w.x * bflo(r0v[p].y) + w.y * bfhi(r0v[p].y)
                + w.z * bflo(r1v[p].y) + w.w * bfhi(r1v[p].y);
        }
    }
    uint32_t r = ((uint32_t)f2bf(a1) << 16) | (uint32_t)f2bf(a0);
    sampled[(size_t)qg * 128 + h * 16 + ln] = r;
}

// ---------------------------------------------------------------------------
// K3a: out-projection, proj_gemm pattern (unchanged, known good).
// ---------------------------------------------------------------------------
__global__ __launch_bounds__(256, 2) void out_gemm(
    const ushort* __restrict__ sampled, const ushort* __restrict__ w_out_t,
    const float* __restrict__ b_out,    const float* __restrict__ src,
    float* __restrict__ x)
{
    const int tid = threadIdx.x;
    const int wv = tid >> 6, lane = tid & 63;
    const int quad = lane >> 4, ln = lane & 15;
    const int mc = blockIdx.x;          // 0..127
    const int by = blockIdx.y;          // 0..3

    const ushort* bp = w_out_t + (size_t)(by * 64 + ln) * 256 + quad * 8;
    bf16x8 bfr[4][8];
#pragma unroll
    for (int t = 0; t < 4; ++t)
#pragma unroll
        for (int s = 0; s < 8; ++s)
            bfr[t][s] = *(const bf16x8*)(bp + (size_t)t * (16 * 256) + s * 32);

    float bias[4];
#pragma unroll
    for (int t = 0; t < 4; ++t) bias[t] = b_out[by * 64 + t * 16 + ln];

    for (int i = 0; i < 3; ++i) {
        const int base = (mc * 3 + i) * 64;
        if (base >= NQ) break;
        const int row_a = base + wv * 16 + ln;
        const bool va = row_a < NQ;
        const ushort* ap = sampled + (size_t)row_a * 256 + quad * 8;

        bf16x8 af[8];
#pragma unroll
        for (int s = 0; s < 8; ++s) {
            bf16x8 v = {0, 0, 0, 0, 0, 0, 0, 0};
            if (va) v = *(const bf16x8*)(ap + s * 32);
            af[s] = v;
        }

        f32x4 acc[4] = {{0,0,0,0},{0,0,0,0},{0,0,0,0},{0,0,0,0}};
#pragma unroll
        for (int s = 0; s < 8; ++s)
#pragma unroll
            for (int t = 0; t < 4; ++t)
                acc[t] = __builtin_amdgcn_mfma_f32_16x16x32_bf16(af[s], bfr[t][s], acc[t], 0, 0, 0);

#pragma unroll
        for (int t = 0; t < 4; ++t) {
            const int col = by * 64 + t * 16 + ln;
#pragma unroll
            for (int reg = 0; reg < 4; ++reg) {
                int row = base + wv * 16 + quad * 4 + reg;
                if (row < NQ)
                    x[(size_t)row * 256 + col] =
                        acc[t][reg] + bias[t] + src[(size_t)row * 256 + col];
            }
        }
    }
}

// ---------------------------------------------------------------------------
// K3b: LayerNorm.  One wave per row, float4 per lane (unchanged, known good).
// ---------------------------------------------------------------------------
__global__ __launch_bounds__(256) void ln_kernel(
    const float* __restrict__ x, const float* __restrict__ gamma,
    const float* __restrict__ beta, float* __restrict__ out)
{
    const int row  = blockIdx.x * 4 + (threadIdx.x >> 6);
    const int lane = threadIdx.x & 63;
    float4 v = *(const float4*)(x + (size_t)row * 256 + lane * 4);
    float s  = v.x + v.y + v.z + v.w;
    float s2 = v.x * v.x + v.y * v.y + v.z * v.z + v.w * v.w;
#pragma unroll
    for (int o = 32; o; o >>= 1) {
        s  += __shfl_xor(s, o);
        s2 += __shfl_xor(s2, o);
    }
    float mu  = s * (1.f / 256.f);
    float var = s2 * (1.f / 256.f) - mu * mu;
    float rs  = rsqrtf(var + 1e-5f);
    float4 g = *(const float4*)(gamma + lane * 4);
    float4 b = *(const float4*)(beta + lane * 4);
    float4 o4;
    o4.x = (v.x - mu) * rs * g.x + b.x;
    o4.y = (v.y - mu) * rs * g.y + b.y;
    o4.z = (v.z - mu) * rs * g.z + b.z;
    o4.w = (v.w - mu) * rs * g.w + b.w;
    *(float4*)(out + (size_t)row * 256 + lane * 4) = o4;
}

// ---------------------------------------------------------------------------
extern "C" void kernel_launch(void* const* d_in, const int* in_sizes, int n_in,
                              void* d_out, int out_size, void* d_ws, size_t ws_size,
                              hipStream_t stream)
{
    const float* src     = (const float*)d_in[0];
    const float* refp    = (const float*)d_in[1];
    const float* w_value = (const float*)d_in[4];
    const float* b_value = (const float*)d_in[5];
    const float* w_off   = (const float*)d_in[6];
    const float* b_off   = (const float*)d_in[7];
    const float* w_attn  = (const float*)d_in[8];
    const float* b_attn  = (const float*)d_in[9];
    const float* w_out   = (const float*)d_in[10];
    const float* b_out   = (const float*)d_in[11];
    const float* gamma   = (const float*)d_in[12];
    const float* beta    = (const float*)d_in[13];

    char* ws = (char*)d_ws;
    ushort*   val_t    = (ushort*)  (ws);                   // 12,533,760 B
    uint32_t* val_pair = (uint32_t*)(ws + 12533760);        // 25,067,520 B
    ushort*   src_bf   = (ushort*)  (ws + 12533760);        // alias of val_pair
                                                            // (src_bf dead before
                                                            //  pair_kernel writes)
    float*    off_raw  = (float*)   (ws + 37601280);        // 25,067,520 B
    float*    attn_raw = (float*)   (ws + 62668800);        // 12,533,760 B
    uint32_t* sampled  = (uint32_t*)(ws + 62668800);        // alias of attn_raw (safe: K2)
    ushort*   B_pack   = (ushort*)  (ws + 75202560);        //    327,680 B
    ushort*   w_out_t  = (ushort*)  (ws + 75530240);        //    131,072 B
    float*    b_pack   = (float*)   (ws + 75661312);        //      2,560 B
    float*    x        = off_raw;                           // alias (off_raw dead after K2)
    float*    out      = (float*)d_out;

    conv_kernel<<<7019, 256, 0, stream>>>(w_value, w_off, w_attn, b_value, b_off,
                                          b_attn, w_out, src, B_pack, w_out_t,
                                          b_pack, src_bf);
    proj_gemm<<<dim3(64, 10), 256, 0, stream>>>(src_bf, B_pack, b_pack, val_t,
                                                off_raw, attn_raw);
    pair_kernel<<<24480, 256, 0, stream>>>(val_t, val_pair);
    sample_kernel<<<12240, 256, 0, stream>>>(refp, val_pair, off_raw, attn_raw,
                                             sampled);
    out_gemm<<<dim3(128, 4), 256, 0, stream>>>((const ushort*)sampled, w_out_t,
                                               b_out, src, x);
    ln_kernel<<<6120, 256, 0, stream>>>(x, gamma, beta, out);
}

// Round 11
// 221.150 us; speedup vs baseline: 1.0554x; 1.0554x over previous
//
#include <hip/hip_runtime.h>
#include <cstdint>
#include <cstddef>

#define D 256
#define HEADS 8
#define HD 32
#define NB 2
#define LQ 12240
#define NQ (NB * LQ)        // 24480
#define PLANE (LQ * HD)     // 391680 elements per (n,h) plane

typedef __attribute__((ext_vector_type(8))) short bf16x8;
typedef __attribute__((ext_vector_type(4))) float f32x4;

__device__ __forceinline__ ushort f2bf(float f) {
    union { float f; uint32_t u; } c; c.f = f;
    uint32_t u = c.u;
    uint32_t r = (u + 0x7fffu + ((u >> 16) & 1u)) >> 16;   // RNE, finite inputs
    return (ushort)r;
}
__device__ __forceinline__ float bflo(uint32_t u) { return __uint_as_float(u << 16); }
__device__ __forceinline__ float bfhi(uint32_t u) { return __uint_as_float(u & 0xffff0000u); }

// ---------------------------------------------------------------------------
// K0: weight/bias conversion + src fp32->bf16 (merged; branches block-uniform).
// ---------------------------------------------------------------------------
__global__ __launch_bounds__(256) void conv_kernel(
    const float* __restrict__ w_value, const float* __restrict__ w_off,
    const float* __restrict__ w_attn,  const float* __restrict__ b_value,
    const float* __restrict__ b_off,   const float* __restrict__ b_attn,
    const float* __restrict__ w_out,   const float* __restrict__ src,
    ushort* __restrict__ B_pack, ushort* __restrict__ w_out_t,
    float* __restrict__ b_pack, ushort* __restrict__ src_bf)
{
    const int b = blockIdx.x, k = threadIdx.x;
    if (b >= 899) {
        const size_t i = ((size_t)(b - 899) * 256 + k) * 4;
        float4 v = *(const float4*)(src + i);
        ushort4 o;
        o.x = f2bf(v.x); o.y = f2bf(v.y); o.z = f2bf(v.z); o.w = f2bf(v.w);
        *(ushort4*)(src_bf + i) = o;
        return;
    }
    if (b < 640) {
        float v;
        if (b < 256)      v = w_value[(size_t)k * 256 + b];
        else if (b < 512) v = w_off[(size_t)k * 256 + (b - 256)];
        else              v = w_attn[(size_t)k * 128 + (b - 512)];
        B_pack[(size_t)b * 256 + k] = f2bf(v);
    } else if (b < 896) {
        int n = b - 640;
        w_out_t[(size_t)n * 256 + k] = f2bf(w_out[(size_t)k * 256 + n]);
    } else if (b == 896) {
        b_pack[k] = b_value[k];
    } else if (b == 897) {
        b_pack[256 + k] = b_off[k];
    } else {
        if (k < 128) b_pack[512 + k] = b_attn[k];
    }
}

// ---------------------------------------------------------------------------
// K1: fused projections via MFMA -- B-stationary in registers (unchanged,
// known good).
// ---------------------------------------------------------------------------
__global__ __launch_bounds__(256, 2) void proj_gemm(
    const ushort* __restrict__ src_bf, const ushort* __restrict__ B_pack,
    const float* __restrict__ b_pack,
    ushort* __restrict__ val_t, float* __restrict__ off_raw,
    float* __restrict__ attn_raw)
{
    const int tid = threadIdx.x;
    const int wv = tid >> 6, lane = tid & 63;
    const int quad = lane >> 4, ln = lane & 15;
    const int mc = blockIdx.x;          // 0..63
    const int by = blockIdx.y;          // 0..9

    const ushort* bp = B_pack + (size_t)(by * 64 + ln) * 256 + quad * 8;
    bf16x8 bfr[4][8];
#pragma unroll
    for (int t = 0; t < 4; ++t)
#pragma unroll
        for (int s = 0; s < 8; ++s)
            bfr[t][s] = *(const bf16x8*)(bp + (size_t)t * (16 * 256) + s * 32);

    float bias[4];
#pragma unroll
    for (int t = 0; t < 4; ++t) bias[t] = b_pack[by * 64 + t * 16 + ln];

    for (int i = 0; i < 6; ++i) {
        const int base = (mc * 6 + i) * 64;
        if (base >= NQ) break;
        const int row_a = base + wv * 16 + ln;
        const bool va = row_a < NQ;
        const ushort* ap = src_bf + (size_t)row_a * 256 + quad * 8;

        bf16x8 af[8];
#pragma unroll
        for (int s = 0; s < 8; ++s) {
            bf16x8 v = {0, 0, 0, 0, 0, 0, 0, 0};
            if (va) v = *(const bf16x8*)(ap + s * 32);
            af[s] = v;
        }

        f32x4 acc[4] = {{0,0,0,0},{0,0,0,0},{0,0,0,0},{0,0,0,0}};
#pragma unroll
        for (int s = 0; s < 8; ++s)
#pragma unroll
            for (int t = 0; t < 4; ++t)
                acc[t] = __builtin_amdgcn_mfma_f32_16x16x32_bf16(af[s], bfr[t][s], acc[t], 0, 0, 0);

        if (by < 4) {
#pragma unroll
            for (int t = 0; t < 4; ++t) {
                const int n_g = by * 64 + t * 16 + ln;
                const int h = n_g >> 5, hd = n_g & 31;
#pragma unroll
                for (int reg = 0; reg < 4; ++reg) {
                    int row = base + wv * 16 + quad * 4 + reg;
                    if (row < NQ) {
                        int nb = row >= LQ; int ql = row - nb * LQ;
                        val_t[(((size_t)(nb * 8 + h)) * LQ + ql) * 32 + hd] =
                            f2bf(acc[t][reg] + bias[t]);
                    }
                }
            }
        } else if (by < 8) {
#pragma unroll
            for (int t = 0; t < 4; ++t) {
                const int col = (by - 4) * 64 + t * 16 + ln;
#pragma unroll
                for (int reg = 0; reg < 4; ++reg) {
                    int row = base + wv * 16 + quad * 4 + reg;
                    if (row < NQ)
                        off_raw[(size_t)row * 256 + col] = acc[t][reg] + bias[t];
                }
            }
        } else {
#pragma unroll
            for (int t = 0; t < 4; ++t) {
                const int col = (by - 8) * 64 + t * 16 + ln;
#pragma unroll
                for (int reg = 0; reg < 4; ++reg) {
                    int row = base + wv * 16 + quad * 4 + reg;
                    if (row < NQ)
                        attn_raw[(size_t)row * 128 + col] = acc[t][reg] + bias[t];
                }
            }
        }
    }
}

// ---------------------------------------------------------------------------
// K1b: build x-pair table (unchanged).
// ---------------------------------------------------------------------------
__global__ __launch_bounds__(256) void pair_kernel(
    const ushort* __restrict__ val_t, uint32_t* __restrict__ val_pair)
{
    const uint32_t i = blockIdx.x * 256 + threadIdx.x;   // < 6,266,880
    const uint32_t c = i & 31;
    const uint32_t rest = i >> 5;                        // plane*12240 + pos
    const uint32_t plane = rest / LQ;
    const uint32_t pos = rest - plane * LQ;
    int l = (pos >= 9216) + (pos >= 11520) + (pos >= 12096);
    uint32_t s0 = (l > 0 ? 9216u : 0u) + (l > 1 ? 2304u : 0u) + (l > 2 ? 576u : 0u);
    uint32_t Wi = 96u >> l;
    uint32_t p = pos - s0;
    uint32_t q = (p / 3u) >> (5 - l);          // p / Wi  (Wi = 3<<(5-l))
    uint32_t xr = p - q * Wi;                  // p % Wi
    uint32_t nxt = (xr == Wi - 1u) ? pos : pos + 1u;
    uint32_t lo = val_t[(size_t)plane * PLANE + pos * 32 + c];
    uint32_t hi = val_t[(size_t)plane * PLANE + nxt * 32 + c];
    val_pair[i] = lo | (hi << 16);
}

// ---------------------------------------------------------------------------
// K2: softmax + sampling + bilinear gather.
// Row-split gather: within each 16-lane group, lanes 0-7 own row0 and lanes
// 8-15 own row1 of every point; each lane loads ONE uint4 (16 B, 4 channel-
// pairs) per point -> 16 loads/lane (was 32), 16 B/lane coalescing sweet
// spot, serial latency chain halved by construction.  Row partials combined
// via shfl_xor(.,8,16); lanes 0-7 store uint2.
// sm_i/sm_w padded to [16][17] -> group offsets hit distinct banks (R10's
// 4-way conflict eliminated).  h = blockIdx%8 XCD partition kept.
// `sampled` aliases `attn_raw` (group reads words 0..15 then writes words
// 0..15 afterwards, same wave) -> safe.
// ---------------------------------------------------------------------------
__global__ __launch_bounds__(256) void sample_kernel(
    const float* __restrict__ ref_pts,
    const uint32_t* __restrict__ val_pair,
    const float* __restrict__ off_raw,
    const float* attn_raw,
    uint32_t* sampled)
{
    __shared__ uint2  sm_i[16][17];
    __shared__ float4 sm_w[16][17];
    const int gl = threadIdx.x >> 4;
    const int ln = threadIdx.x & 15;
    const int h     = blockIdx.x & 7;        // -> XCD id (heuristic)
    const int chunk = blockIdx.x >> 3;       // 0..1529
    const int qg = chunk * 16 + gl;
    const int n  = (qg >= LQ) ? 1 : 0;
    const int l  = ln >> 2;

    // softmax over 16 (level,point) logits of this head
    float a = attn_raw[(size_t)qg * 128 + h * 16 + ln];
    float m = a;
#pragma unroll
    for (int s = 8; s; s >>= 1) m = fmaxf(m, __shfl_xor(m, s, 16));
    float e = __expf(a - m);
    float ssum = e;
#pragma unroll
    for (int s = 8; s; s >>= 1) ssum += __shfl_xor(ssum, s, 16);
    float aw = e / ssum;

    float ox = off_raw[(size_t)qg * 256 + h * 32 + ln * 2 + 0];
    float oy = off_raw[(size_t)qg * 256 + h * 32 + ln * 2 + 1];
    float rx = ref_pts[(qg * 4 + l) * 2 + 0];
    float ry = ref_pts[(qg * 4 + l) * 2 + 1];

    const int Wi = 96 >> l;
    const int Hi = Wi;
    const int s0 = (l > 0 ? 9216 : 0) + (l > 1 ? 2304 : 0) + (l > 2 ? 576 : 0);
    const float Wf = (float)Wi, Hf = (float)Hi;

    float x = (rx + ox / Wf) * Wf - 0.5f;
    float y = (ry + oy / Hf) * Hf - 0.5f;
    float x0f = floorf(x), y0f = floorf(y);
    float lx = x - x0f, ly = y - y0f;
    int x0 = (int)x0f, y0 = (int)y0f;

    float wy0 = (y0 >= 0 && y0 < Hi) ? (1.f - ly) : 0.f;
    float wy1 = (y0 + 1 >= 0 && y0 + 1 < Hi) ? ly : 0.f;
    int yc0 = min(max(y0, 0), Hi - 1);
    int yc1 = min(max(y0 + 1, 0), Hi - 1);
    float wl = (x0 >= 0 && x0 < Wi) ? (1.f - lx) : 0.f;
    float wh = (x0 + 1 >= 0 && x0 + 1 < Wi) ? lx : 0.f;
    float pl, ph;
    int xe;
    if (x0 < 0) { pl = wh; ph = 0.f; xe = x0 + 1; }
    else        { pl = wl; ph = wh;  xe = x0; }
    int xc = min(max(xe, 0), Wi - 1);
    pl *= aw; ph *= aw;

    sm_i[gl][ln] = make_uint2((uint32_t)(s0 + yc0 * Wi + xc) * 32u,
                              (uint32_t)(s0 + yc1 * Wi + xc) * 32u);
    sm_w[gl][ln] = make_float4(pl * wy0, ph * wy0, pl * wy1, ph * wy1);
    // intra-wave LDS write->read: same-wave DS ops execute in order

    const int half = ln >> 3;              // 0: row0, 1: row1
    const int cb   = (ln & 7) * 4;         // u32 channel-pair base
    const uint32_t* plane =
        val_pair + (size_t)(n * HEADS + h) * PLANE + cb;

    float a0 = 0.f, a1 = 0.f, a2 = 0.f, a3 = 0.f;
#pragma unroll
    for (int c = 0; c < 2; ++c) {
        uint4  rv[8];
        float2 wv2[8];
#pragma unroll
        for (int p = 0; p < 8; ++p) {
            uint2 ent = sm_i[gl][c * 8 + p];
            uint32_t off = half ? ent.y : ent.x;
            rv[p] = *(const uint4*)(plane + off);
            float4 w = sm_w[gl][c * 8 + p];
            wv2[p] = half ? make_float2(w.z, w.w) : make_float2(w.x, w.y);
        }
#pragma unroll
        for (int p = 0; p < 8; ++p) {
            float2 w = wv2[p];
            a0 += w.x * bflo(rv[p].x) + w.y * bfhi(rv[p].x);
            a1 += w.x * bflo(rv[p].y) + w.y * bfhi(rv[p].y);
            a2 += w.x * bflo(rv[p].z) + w.y * bfhi(rv[p].z);
            a3 += w.x * bflo(rv[p].w) + w.y * bfhi(rv[p].w);
        }
    }
    // combine row0 + row1 partials (lanes ln and ln^8 hold the same channels)
    a0 += __shfl_xor(a0, 8, 16);
    a1 += __shfl_xor(a1, 8, 16);
    a2 += __shfl_xor(a2, 8, 16);
    a3 += __shfl_xor(a3, 8, 16);
    if (ln < 8) {
        uint2 rr;
        rr.x = ((uint32_t)f2bf(a1) << 16) | (uint32_t)f2bf(a0);
        rr.y = ((uint32_t)f2bf(a3) << 16) | (uint32_t)f2bf(a2);
        *(uint2*)(sampled + (size_t)qg * 128 + h * 16 + 2 * ln) = rr;
    }
}

// ---------------------------------------------------------------------------
// K3a: out-projection, proj_gemm pattern (unchanged, known good).
// ---------------------------------------------------------------------------
__global__ __launch_bounds__(256, 2) void out_gemm(
    const ushort* __restrict__ sampled, const ushort* __restrict__ w_out_t,
    const float* __restrict__ b_out,    const float* __restrict__ src,
    float* __restrict__ x)
{
    const int tid = threadIdx.x;
    const int wv = tid >> 6, lane = tid & 63;
    const int quad = lane >> 4, ln = lane & 15;
    const int mc = blockIdx.x;          // 0..127
    const int by = blockIdx.y;          // 0..3

    const ushort* bp = w_out_t + (size_t)(by * 64 + ln) * 256 + quad * 8;
    bf16x8 bfr[4][8];
#pragma unroll
    for (int t = 0; t < 4; ++t)
#pragma unroll
        for (int s = 0; s < 8; ++s)
            bfr[t][s] = *(const bf16x8*)(bp + (size_t)t * (16 * 256) + s * 32);

    float bias[4];
#pragma unroll
    for (int t = 0; t < 4; ++t) bias[t] = b_out[by * 64 + t * 16 + ln];

    for (int i = 0; i < 3; ++i) {
        const int base = (mc * 3 + i) * 64;
        if (base >= NQ) break;
        const int row_a = base + wv * 16 + ln;
        const bool va = row_a < NQ;
        const ushort* ap = sampled + (size_t)row_a * 256 + quad * 8;

        bf16x8 af[8];
#pragma unroll
        for (int s = 0; s < 8; ++s) {
            bf16x8 v = {0, 0, 0, 0, 0, 0, 0, 0};
            if (va) v = *(const bf16x8*)(ap + s * 32);
            af[s] = v;
        }

        f32x4 acc[4] = {{0,0,0,0},{0,0,0,0},{0,0,0,0},{0,0,0,0}};
#pragma unroll
        for (int s = 0; s < 8; ++s)
#pragma unroll
            for (int t = 0; t < 4; ++t)
                acc[t] = __builtin_amdgcn_mfma_f32_16x16x32_bf16(af[s], bfr[t][s], acc[t], 0, 0, 0);

#pragma unroll
        for (int t = 0; t < 4; ++t) {
            const int col = by * 64 + t * 16 + ln;
#pragma unroll
            for (int reg = 0; reg < 4; ++reg) {
                int row = base + wv * 16 + quad * 4 + reg;
                if (row < NQ)
                    x[(size_t)row * 256 + col] =
                        acc[t][reg] + bias[t] + src[(size_t)row * 256 + col];
            }
        }
    }
}

// ---------------------------------------------------------------------------
// K3b: LayerNorm.  One wave per row, float4 per lane (unchanged, known good).
// ---------------------------------------------------------------------------
__global__ __launch_bounds__(256) void ln_kernel(
    const float* __restrict__ x, const float* __restrict__ gamma,
    const float* __restrict__ beta, float* __restrict__ out)
{
    const int row  = blockIdx.x * 4 + (threadIdx.x >> 6);
    const int lane = threadIdx.x & 63;
    float4 v = *(const float4*)(x + (size_t)row * 256 + lane * 4);
    float s  = v.x + v.y + v.z + v.w;
    float s2 = v.x * v.x + v.y * v.y + v.z * v.z + v.w * v.w;
#pragma unroll
    for (int o = 32; o; o >>= 1) {
        s  += __shfl_xor(s, o);
        s2 += __shfl_xor(s2, o);
    }
    float mu  = s * (1.f / 256.f);
    float var = s2 * (1.f / 256.f) - mu * mu;
    float rs  = rsqrtf(var + 1e-5f);
    float4 g = *(const float4*)(gamma + lane * 4);
    float4 b = *(const float4*)(beta + lane * 4);
    float4 o4;
    o4.x = (v.x - mu) * rs * g.x + b.x;
    o4.y = (v.y - mu) * rs * g.y + b.y;
    o4.z = (v.z - mu) * rs * g.z + b.z;
    o4.w = (v.w - mu) * rs * g.w + b.w;
    *(float4*)(out + (size_t)row * 256 + lane * 4) = o4;
}

// ---------------------------------------------------------------------------
extern "C" void kernel_launch(void* const* d_in, const int* in_sizes, int n_in,
                              void* d_out, int out_size, void* d_ws, size_t ws_size,
                              hipStream_t stream)
{
    const float* src     = (const float*)d_in[0];
    const float* refp    = (const float*)d_in[1];
    const float* w_value = (const float*)d_in[4];
    const float* b_value = (const float*)d_in[5];
    const float* w_off   = (const float*)d_in[6];
    const float* b_off   = (const float*)d_in[7];
    const float* w_attn  = (const float*)d_in[8];
    const float* b_attn  = (const float*)d_in[9];
    const float* w_out   = (const float*)d_in[10];
    const float* b_out   = (const float*)d_in[11];
    const float* gamma   = (const float*)d_in[12];
    const float* beta    = (const float*)d_in[13];

    char* ws = (char*)d_ws;
    ushort*   val_t    = (ushort*)  (ws);                   // 12,533,760 B
    uint32_t* val_pair = (uint32_t*)(ws + 12533760);        // 25,067,520 B
    ushort*   src_bf   = (ushort*)  (ws + 12533760);        // alias of val_pair
                                                            // (src_bf dead before
                                                            //  pair_kernel writes)
    float*    off_raw  = (float*)   (ws + 37601280);        // 25,067,520 B
    float*    attn_raw = (float*)   (ws + 62668800);        // 12,533,760 B
    uint32_t* sampled  = (uint32_t*)(ws + 62668800);        // alias of attn_raw (safe: K2)
    ushort*   B_pack   = (ushort*)  (ws + 75202560);        //    327,680 B
    ushort*   w_out_t  = (ushort*)  (ws + 75530240);        //    131,072 B
    float*    b_pack   = (float*)   (ws + 75661312);        //      2,560 B
    float*    x        = off_raw;                           // alias (off_raw dead after K2)
    float*    out      = (float*)d_out;

    conv_kernel<<<7019, 256, 0, stream>>>(w_value, w_off, w_attn, b_value, b_off,
                                          b_attn, w_out, src, B_pack, w_out_t,
                                          b_pack, src_bf);
    proj_gemm<<<dim3(64, 10), 256, 0, stream>>>(src_bf, B_pack, b_pack, val_t,
                                                off_raw, attn_raw);
    pair_kernel<<<24480, 256, 0, stream>>>(val_t, val_pair);
    sample_kernel<<<12240, 256, 0, stream>>>(refp, val_pair, off_raw, attn_raw,
                                             sampled);
    out_gemm<<<dim3(128, 4), 256, 0, stream>>>((const ushort*)sampled, w_out_t,
                                               b_out, src, x);
    ln_kernel<<<6120, 256, 0, stream>>>(x, gamma, beta, out);
}

// Round 12
// 211.472 us; speedup vs baseline: 1.1037x; 1.0458x over previous
//
#include <hip/hip_runtime.h>
#include <cstdint>
#include <cstddef>

#define D 256
#define HEADS 8
#define HD 32
#define NB 2
#define LQ 12240
#define NQ (NB * LQ)        // 24480
#define PLANE (LQ * HD)     // 391680 elements per (n,h) plane

typedef __attribute__((ext_vector_type(8))) short bf16x8;
typedef __attribute__((ext_vector_type(4))) float f32x4;
typedef __bf16 bf16x2 __attribute__((ext_vector_type(2)));

__device__ __forceinline__ ushort f2bf(float f) {
    union { float f; uint32_t u; } c; c.f = f;
    uint32_t u = c.u;
    uint32_t r = (u + 0x7fffu + ((u >> 16) & 1u)) >> 16;   // RNE, finite inputs
    return (ushort)r;
}
__device__ __forceinline__ float bflo(uint32_t u) { return __uint_as_float(u << 16); }
__device__ __forceinline__ float bfhi(uint32_t u) { return __uint_as_float(u & 0xffff0000u); }

// c += a_pair . b_pair  (bf16 pairs packed in u32, f32 accumulate)
__device__ __forceinline__ float dot2bf(uint32_t a, uint32_t b, float c) {
#if __has_builtin(__builtin_amdgcn_fdot2_f32_bf16)
    return __builtin_amdgcn_fdot2_f32_bf16(__builtin_bit_cast(bf16x2, a),
                                           __builtin_bit_cast(bf16x2, b), c, false);
#else
    return c + bflo(a) * bflo(b) + bfhi(a) * bfhi(b);
#endif
}

// ---------------------------------------------------------------------------
// K0: weight/bias conversion + src fp32->bf16 (merged; branches block-uniform).
// ---------------------------------------------------------------------------
__global__ __launch_bounds__(256) void conv_kernel(
    const float* __restrict__ w_value, const float* __restrict__ w_off,
    const float* __restrict__ w_attn,  const float* __restrict__ b_value,
    const float* __restrict__ b_off,   const float* __restrict__ b_attn,
    const float* __restrict__ w_out,   const float* __restrict__ src,
    ushort* __restrict__ B_pack, ushort* __restrict__ w_out_t,
    float* __restrict__ b_pack, ushort* __restrict__ src_bf)
{
    const int b = blockIdx.x, k = threadIdx.x;
    if (b >= 899) {
        const size_t i = ((size_t)(b - 899) * 256 + k) * 4;
        float4 v = *(const float4*)(src + i);
        ushort4 o;
        o.x = f2bf(v.x); o.y = f2bf(v.y); o.z = f2bf(v.z); o.w = f2bf(v.w);
        *(ushort4*)(src_bf + i) = o;
        return;
    }
    if (b < 640) {
        float v;
        if (b < 256)      v = w_value[(size_t)k * 256 + b];
        else if (b < 512) v = w_off[(size_t)k * 256 + (b - 256)];
        else              v = w_attn[(size_t)k * 128 + (b - 512)];
        B_pack[(size_t)b * 256 + k] = f2bf(v);
    } else if (b < 896) {
        int n = b - 640;
        w_out_t[(size_t)n * 256 + k] = f2bf(w_out[(size_t)k * 256 + n]);
    } else if (b == 896) {
        b_pack[k] = b_value[k];
    } else if (b == 897) {
        b_pack[256 + k] = b_off[k];
    } else {
        if (k < 128) b_pack[512 + k] = b_attn[k];
    }
}

// ---------------------------------------------------------------------------
// K1: fused projections via MFMA -- B-stationary in registers (unchanged,
// known good).
// ---------------------------------------------------------------------------
__global__ __launch_bounds__(256, 2) void proj_gemm(
    const ushort* __restrict__ src_bf, const ushort* __restrict__ B_pack,
    const float* __restrict__ b_pack,
    ushort* __restrict__ val_t, float* __restrict__ off_raw,
    float* __restrict__ attn_raw)
{
    const int tid = threadIdx.x;
    const int wv = tid >> 6, lane = tid & 63;
    const int quad = lane >> 4, ln = lane & 15;
    const int mc = blockIdx.x;          // 0..63
    const int by = blockIdx.y;          // 0..9

    const ushort* bp = B_pack + (size_t)(by * 64 + ln) * 256 + quad * 8;
    bf16x8 bfr[4][8];
#pragma unroll
    for (int t = 0; t < 4; ++t)
#pragma unroll
        for (int s = 0; s < 8; ++s)
            bfr[t][s] = *(const bf16x8*)(bp + (size_t)t * (16 * 256) + s * 32);

    float bias[4];
#pragma unroll
    for (int t = 0; t < 4; ++t) bias[t] = b_pack[by * 64 + t * 16 + ln];

    for (int i = 0; i < 6; ++i) {
        const int base = (mc * 6 + i) * 64;
        if (base >= NQ) break;
        const int row_a = base + wv * 16 + ln;
        const bool va = row_a < NQ;
        const ushort* ap = src_bf + (size_t)row_a * 256 + quad * 8;

        bf16x8 af[8];
#pragma unroll
        for (int s = 0; s < 8; ++s) {
            bf16x8 v = {0, 0, 0, 0, 0, 0, 0, 0};
            if (va) v = *(const bf16x8*)(ap + s * 32);
            af[s] = v;
        }

        f32x4 acc[4] = {{0,0,0,0},{0,0,0,0},{0,0,0,0},{0,0,0,0}};
#pragma unroll
        for (int s = 0; s < 8; ++s)
#pragma unroll
            for (int t = 0; t < 4; ++t)
                acc[t] = __builtin_amdgcn_mfma_f32_16x16x32_bf16(af[s], bfr[t][s], acc[t], 0, 0, 0);

        if (by < 4) {
#pragma unroll
            for (int t = 0; t < 4; ++t) {
                const int n_g = by * 64 + t * 16 + ln;
                const int h = n_g >> 5, hd = n_g & 31;
#pragma unroll
                for (int reg = 0; reg < 4; ++reg) {
                    int row = base + wv * 16 + quad * 4 + reg;
                    if (row < NQ) {
                        int nb = row >= LQ; int ql = row - nb * LQ;
                        val_t[(((size_t)(nb * 8 + h)) * LQ + ql) * 32 + hd] =
                            f2bf(acc[t][reg] + bias[t]);
                    }
                }
            }
        } else if (by < 8) {
#pragma unroll
            for (int t = 0; t < 4; ++t) {
                const int col = (by - 4) * 64 + t * 16 + ln;
#pragma unroll
                for (int reg = 0; reg < 4; ++reg) {
                    int row = base + wv * 16 + quad * 4 + reg;
                    if (row < NQ)
                        off_raw[(size_t)row * 256 + col] = acc[t][reg] + bias[t];
                }
            }
        } else {
#pragma unroll
            for (int t = 0; t < 4; ++t) {
                const int col = (by - 8) * 64 + t * 16 + ln;
#pragma unroll
                for (int reg = 0; reg < 4; ++reg) {
                    int row = base + wv * 16 + quad * 4 + reg;
                    if (row < NQ)
                        attn_raw[(size_t)row * 128 + col] = acc[t][reg] + bias[t];
                }
            }
        }
    }
}

// ---------------------------------------------------------------------------
// K1b: build x-pair table (unchanged).
// ---------------------------------------------------------------------------
__global__ __launch_bounds__(256) void pair_kernel(
    const ushort* __restrict__ val_t, uint32_t* __restrict__ val_pair)
{
    const uint32_t i = blockIdx.x * 256 + threadIdx.x;   // < 6,266,880
    const uint32_t c = i & 31;
    const uint32_t rest = i >> 5;                        // plane*12240 + pos
    const uint32_t plane = rest / LQ;
    const uint32_t pos = rest - plane * LQ;
    int l = (pos >= 9216) + (pos >= 11520) + (pos >= 12096);
    uint32_t s0 = (l > 0 ? 9216u : 0u) + (l > 1 ? 2304u : 0u) + (l > 2 ? 576u : 0u);
    uint32_t Wi = 96u >> l;
    uint32_t p = pos - s0;
    uint32_t q = (p / 3u) >> (5 - l);          // p / Wi  (Wi = 3<<(5-l))
    uint32_t xr = p - q * Wi;                  // p % Wi
    uint32_t nxt = (xr == Wi - 1u) ? pos : pos + 1u;
    uint32_t lo = val_t[(size_t)plane * PLANE + pos * 32 + c];
    uint32_t hi = val_t[(size_t)plane * PLANE + nxt * 32 + c];
    val_pair[i] = lo | (hi << 16);
}

// ---------------------------------------------------------------------------
// K2: softmax + sampling + bilinear gather.
// Row-split (R11, kept): lanes 0-7 own row0, lanes 8-15 row1; one uint4
// (4 channel-pairs) per point per lane; partials combined via shfl_xor(.,8,16).
// NEW: packed-bf16 weights + v_dot2_f32_bf16 -> 4 dot2/point (was 8 unpack
// + 8 FMA); row select folded into LDS ADDRESS ([16][2][18] layout, `half`
// indexes the middle dim) -> zero v_cndmask in hot loop.  Stride 18 words:
// the 8 distinct broadcast words/instr land on distinct banks.
// h = blockIdx%8 XCD partition kept.  `sampled` aliases `attn_raw` -> safe.
// ---------------------------------------------------------------------------
__global__ __launch_bounds__(256) void sample_kernel(
    const float* __restrict__ ref_pts,
    const uint32_t* __restrict__ val_pair,
    const float* __restrict__ off_raw,
    const float* attn_raw,
    uint32_t* sampled)
{
    __shared__ uint32_t sm_i[16][2][18];
    __shared__ uint32_t sm_w[16][2][18];
    const int gl = threadIdx.x >> 4;
    const int ln = threadIdx.x & 15;
    const int h     = blockIdx.x & 7;        // -> XCD id (heuristic)
    const int chunk = blockIdx.x >> 3;       // 0..1529
    const int qg = chunk * 16 + gl;
    const int n  = (qg >= LQ) ? 1 : 0;
    const int l  = ln >> 2;

    // softmax over 16 (level,point) logits of this head
    float a = attn_raw[(size_t)qg * 128 + h * 16 + ln];
    float m = a;
#pragma unroll
    for (int s = 8; s; s >>= 1) m = fmaxf(m, __shfl_xor(m, s, 16));
    float e = __expf(a - m);
    float ssum = e;
#pragma unroll
    for (int s = 8; s; s >>= 1) ssum += __shfl_xor(ssum, s, 16);
    float aw = e / ssum;

    float ox = off_raw[(size_t)qg * 256 + h * 32 + ln * 2 + 0];
    float oy = off_raw[(size_t)qg * 256 + h * 32 + ln * 2 + 1];
    float rx = ref_pts[(qg * 4 + l) * 2 + 0];
    float ry = ref_pts[(qg * 4 + l) * 2 + 1];

    const int Wi = 96 >> l;
    const int Hi = Wi;
    const int s0 = (l > 0 ? 9216 : 0) + (l > 1 ? 2304 : 0) + (l > 2 ? 576 : 0);
    const float Wf = (float)Wi, Hf = (float)Hi;

    float x = (rx + ox / Wf) * Wf - 0.5f;
    float y = (ry + oy / Hf) * Hf - 0.5f;
    float x0f = floorf(x), y0f = floorf(y);
    float lx = x - x0f, ly = y - y0f;
    int x0 = (int)x0f, y0 = (int)y0f;

    float wy0 = (y0 >= 0 && y0 < Hi) ? (1.f - ly) : 0.f;
    float wy1 = (y0 + 1 >= 0 && y0 + 1 < Hi) ? ly : 0.f;
    int yc0 = min(max(y0, 0), Hi - 1);
    int yc1 = min(max(y0 + 1, 0), Hi - 1);
    float wl = (x0 >= 0 && x0 < Wi) ? (1.f - lx) : 0.f;
    float wh = (x0 + 1 >= 0 && x0 + 1 < Wi) ? lx : 0.f;
    float pl, ph;
    int xe;
    if (x0 < 0) { pl = wh; ph = 0.f; xe = x0 + 1; }
    else        { pl = wl; ph = wh;  xe = x0; }
    int xc = min(max(xe, 0), Wi - 1);
    pl *= aw; ph *= aw;

    sm_i[gl][0][ln] = (uint32_t)(s0 + yc0 * Wi + xc) * 32u;
    sm_i[gl][1][ln] = (uint32_t)(s0 + yc1 * Wi + xc) * 32u;
    sm_w[gl][0][ln] = ((uint32_t)f2bf(ph * wy0) << 16) | (uint32_t)f2bf(pl * wy0);
    sm_w[gl][1][ln] = ((uint32_t)f2bf(ph * wy1) << 16) | (uint32_t)f2bf(pl * wy1);
    // intra-wave LDS write->read: same-wave DS ops execute in order

    const int half = ln >> 3;              // 0: row0, 1: row1
    const int cb   = (ln & 7) * 4;         // u32 channel-pair base
    const uint32_t* plane =
        val_pair + (size_t)(n * HEADS + h) * PLANE + cb;

    float a0 = 0.f, a1 = 0.f, a2 = 0.f, a3 = 0.f;
#pragma unroll
    for (int c = 0; c < 2; ++c) {
        uint4    rv[8];
        uint32_t wpk[8];
#pragma unroll
        for (int p = 0; p < 8; ++p) {
            uint32_t off = sm_i[gl][half][c * 8 + p];
            rv[p]  = *(const uint4*)(plane + off);
            wpk[p] = sm_w[gl][half][c * 8 + p];
        }
#pragma unroll
        for (int p = 0; p < 8; ++p) {
            a0 = dot2bf(rv[p].x, wpk[p], a0);
            a1 = dot2bf(rv[p].y, wpk[p], a1);
            a2 = dot2bf(rv[p].z, wpk[p], a2);
            a3 = dot2bf(rv[p].w, wpk[p], a3);
        }
    }
    // combine row0 + row1 partials (lanes ln and ln^8 hold the same channels)
    a0 += __shfl_xor(a0, 8, 16);
    a1 += __shfl_xor(a1, 8, 16);
    a2 += __shfl_xor(a2, 8, 16);
    a3 += __shfl_xor(a3, 8, 16);
    if (ln < 8) {
        uint2 rr;
        rr.x = ((uint32_t)f2bf(a1) << 16) | (uint32_t)f2bf(a0);
        rr.y = ((uint32_t)f2bf(a3) << 16) | (uint32_t)f2bf(a2);
        *(uint2*)(sampled + (size_t)qg * 128 + h * 16 + 2 * ln) = rr;
    }
}

// ---------------------------------------------------------------------------
// K3a: out-projection, proj_gemm pattern (unchanged, known good).
// ---------------------------------------------------------------------------
__global__ __launch_bounds__(256, 2) void out_gemm(
    const ushort* __restrict__ sampled, const ushort* __restrict__ w_out_t,
    const float* __restrict__ b_out,    const float* __restrict__ src,
    float* __restrict__ x)
{
    const int tid = threadIdx.x;
    const int wv = tid >> 6, lane = tid & 63;
    const int quad = lane >> 4, ln = lane & 15;
    const int mc = blockIdx.x;          // 0..127
    const int by = blockIdx.y;          // 0..3

    const ushort* bp = w_out_t + (size_t)(by * 64 + ln) * 256 + quad * 8;
    bf16x8 bfr[4][8];
#pragma unroll
    for (int t = 0; t < 4; ++t)
#pragma unroll
        for (int s = 0; s < 8; ++s)
            bfr[t][s] = *(const bf16x8*)(bp + (size_t)t * (16 * 256) + s * 32);

    float bias[4];
#pragma unroll
    for (int t = 0; t < 4; ++t) bias[t] = b_out[by * 64 + t * 16 + ln];

    for (int i = 0; i < 3; ++i) {
        const int base = (mc * 3 + i) * 64;
        if (base >= NQ) break;
        const int row_a = base + wv * 16 + ln;
        const bool va = row_a < NQ;
        const ushort* ap = sampled + (size_t)row_a * 256 + quad * 8;

        bf16x8 af[8];
#pragma unroll
        for (int s = 0; s < 8; ++s) {
            bf16x8 v = {0, 0, 0, 0, 0, 0, 0, 0};
            if (va) v = *(const bf16x8*)(ap + s * 32);
            af[s] = v;
        }

        f32x4 acc[4] = {{0,0,0,0},{0,0,0,0},{0,0,0,0},{0,0,0,0}};
#pragma unroll
        for (int s = 0; s < 8; ++s)
#pragma unroll
            for (int t = 0; t < 4; ++t)
                acc[t] = __builtin_amdgcn_mfma_f32_16x16x32_bf16(af[s], bfr[t][s], acc[t], 0, 0, 0);

#pragma unroll
        for (int t = 0; t < 4; ++t) {
            const int col = by * 64 + t * 16 + ln;
#pragma unroll
            for (int reg = 0; reg < 4; ++reg) {
                int row = base + wv * 16 + quad * 4 + reg;
                if (row < NQ)
                    x[(size_t)row * 256 + col] =
                        acc[t][reg] + bias[t] + src[(size_t)row * 256 + col];
            }
        }
    }
}

// ---------------------------------------------------------------------------
// K3b: LayerNorm.  One wave per row, float4 per lane (unchanged, known good).
// ---------------------------------------------------------------------------
__global__ __launch_bounds__(256) void ln_kernel(
    const float* __restrict__ x, const float* __restrict__ gamma,
    const float* __restrict__ beta, float* __restrict__ out)
{
    const int row  = blockIdx.x * 4 + (threadIdx.x >> 6);
    const int lane = threadIdx.x & 63;
    float4 v = *(const float4*)(x + (size_t)row * 256 + lane * 4);
    float s  = v.x + v.y + v.z + v.w;
    float s2 = v.x * v.x + v.y * v.y + v.z * v.z + v.w * v.w;
#pragma unroll
    for (int o = 32; o; o >>= 1) {
        s  += __shfl_xor(s, o);
        s2 += __shfl_xor(s2, o);
    }
    float mu  = s * (1.f / 256.f);
    float var = s2 * (1.f / 256.f) - mu * mu;
    float rs  = rsqrtf(var + 1e-5f);
    float4 g = *(const float4*)(gamma + lane * 4);
    float4 b = *(const float4*)(beta + lane * 4);
    float4 o4;
    o4.x = (v.x - mu) * rs * g.x + b.x;
    o4.y = (v.y - mu) * rs * g.y + b.y;
    o4.z = (v.z - mu) * rs * g.z + b.z;
    o4.w = (v.w - mu) * rs * g.w + b.w;
    *(float4*)(out + (size_t)row * 256 + lane * 4) = o4;
}

// ---------------------------------------------------------------------------
extern "C" void kernel_launch(void* const* d_in, const int* in_sizes, int n_in,
                              void* d_out, int out_size, void* d_ws, size_t ws_size,
                              hipStream_t stream)
{
    const float* src     = (const float*)d_in[0];
    const float* refp    = (const float*)d_in[1];
    const float* w_value = (const float*)d_in[4];
    const float* b_value = (const float*)d_in[5];
    const float* w_off   = (const float*)d_in[6];
    const float* b_off   = (const float*)d_in[7];
    const float* w_attn  = (const float*)d_in[8];
    const float* b_attn  = (const float*)d_in[9];
    const float* w_out   = (const float*)d_in[10];
    const float* b_out   = (const float*)d_in[11];
    const float* gamma   = (const float*)d_in[12];
    const float* beta    = (const float*)d_in[13];

    char* ws = (char*)d_ws;
    ushort*   val_t    = (ushort*)  (ws);                   // 12,533,760 B
    uint32_t* val_pair = (uint32_t*)(ws + 12533760);        // 25,067,520 B
    ushort*   src_bf   = (ushort*)  (ws + 12533760);        // alias of val_pair
                                                            // (src_bf dead before
                                                            //  pair_kernel writes)
    float*    off_raw  = (float*)   (ws + 37601280);        // 25,067,520 B
    float*    attn_raw = (float*)   (ws + 62668800);        // 12,533,760 B
    uint32_t* sampled  = (uint32_t*)(ws + 62668800);        // alias of attn_raw (safe: K2)
    ushort*   B_pack   = (ushort*)  (ws + 75202560);        //    327,680 B
    ushort*   w_out_t  = (ushort*)  (ws + 75530240);        //    131,072 B
    float*    b_pack   = (float*)   (ws + 75661312);        //      2,560 B
    float*    x        = off_raw;                           // alias (off_raw dead after K2)
    float*    out      = (float*)d_out;

    conv_kernel<<<7019, 256, 0, stream>>>(w_value, w_off, w_attn, b_value, b_off,
                                          b_attn, w_out, src, B_pack, w_out_t,
                                          b_pack, src_bf);
    proj_gemm<<<dim3(64, 10), 256, 0, stream>>>(src_bf, B_pack, b_pack, val_t,
                                                off_raw, attn_raw);
    pair_kernel<<<24480, 256, 0, stream>>>(val_t, val_pair);
    sample_kernel<<<12240, 256, 0, stream>>>(refp, val_pair, off_raw, attn_raw,
                                             sampled);
    out_gemm<<<dim3(128, 4), 256, 0, stream>>>((const ushort*)sampled, w_out_t,
                                               b_out, src, x);
    ln_kernel<<<6120, 256, 0, stream>>>(x, gamma, beta, out);
}